// Round 2
// 347.519 us; speedup vs baseline: 1.0136x; 1.0136x over previous
//
#include <hip/hip_runtime.h>
#include <hip/hip_bf16.h>

typedef short bf16x8 __attribute__((ext_vector_type(8)));
typedef float f32x4 __attribute__((ext_vector_type(4)));

#define BSH 7            // 128 targets per bucket
#define BK  (1 << BSH)

static inline int cdiv(int a, int b){ return (a + b - 1) / b; }

__device__ __forceinline__ unsigned pack_bf16_hi(float v){
    return ((unsigned)__bfloat16_as_ushort(__float2bfloat16(v))) << 16;
}
__device__ __forceinline__ float bf16hi_to_f32(unsigned bits_hi16){
    return __uint_as_float(bits_hi16);  // bf16 bits already in [31:16]
}

// ---------- pass 0: global bucket histogram (LDS-privatized) ----------
__global__ __launch_bounds__(256) void k_bcnt0(const int* __restrict__ tgt,
                                               int* __restrict__ gcnt, int E, int NB){
    __shared__ int lh[1024];
    int tid = threadIdx.x;
    for (int b = tid; b < 1024; b += 256) lh[b] = 0;
    __syncthreads();
    int c0 = blockIdx.x * 4096;
    #pragma unroll
    for (int u = 0; u < 16; ++u){
        int e = c0 + u * 256 + tid;
        if (e < E) atomicAdd(&lh[tgt[e] >> BSH], 1);
    }
    __syncthreads();
    for (int b = tid; b < NB; b += 256){
        int c = lh[b];
        if (c) atomicAdd(&gcnt[b], c);
    }
}

// ---------- pass 0.5: scan bucket counts -> bases (= CSR bucket bases) ----------
__global__ __launch_bounds__(256) void k_bscan(const int* __restrict__ gcnt,
                                               int* __restrict__ bbase,
                                               int* __restrict__ gcur,
                                               int* __restrict__ rs,
                                               int N, int E){
    __shared__ int sc[256];
    int tid = threadIdx.x;
    int b0 = tid * 4;
    int v0 = gcnt[b0], v1 = gcnt[b0 + 1], v2 = gcnt[b0 + 2], v3 = gcnt[b0 + 3];
    int t3 = v0 + v1 + v2 + v3;
    sc[tid] = t3;
    __syncthreads();
    for (int off = 1; off < 256; off <<= 1){
        int x = (tid >= off) ? sc[tid - off] : 0;
        __syncthreads();
        sc[tid] += x;
        __syncthreads();
    }
    int ex = sc[tid] - t3;
    bbase[b0]     = ex;
    bbase[b0 + 1] = ex + v0;
    bbase[b0 + 2] = ex + v0 + v1;
    bbase[b0 + 3] = ex + v0 + v1 + v2;
    gcur[b0] = bbase[b0]; gcur[b0 + 1] = bbase[b0 + 1];
    gcur[b0 + 2] = bbase[b0 + 2]; gcur[b0 + 3] = bbase[b0 + 3];
    if (tid == 255) bbase[1024] = sc[255];   // == E
    if (tid == 0)   rs[N] = E;
}

// ---------- pass 1: bin edges into bucket-contiguous regions (direct write) ----------
__global__ __launch_bounds__(256) void k_bin(
        const int* __restrict__ src, const int* __restrict__ tgt,
        const float* __restrict__ asp, const float* __restrict__ actx,
        const float* __restrict__ alat, const float* __restrict__ wsp,
        const float* __restrict__ wctx, const float* __restrict__ wlat,
        int* __restrict__ gcur, uint4* __restrict__ binned, int E, int NB){
    __shared__ int lh[1024], lc[1024], gb[1024];
    int tid = threadIdx.x;
    int c0 = blockIdx.x * 4096;
    for (int b = tid; b < 1024; b += 256){ lh[b] = 0; lc[b] = 0; }
    __syncthreads();
    #pragma unroll
    for (int u = 0; u < 16; ++u){
        int e = c0 + u * 256 + tid;
        if (e < E) atomicAdd(&lh[tgt[e] >> BSH], 1);
    }
    __syncthreads();
    for (int b = tid; b < NB; b += 256){
        int c = lh[b];
        gb[b] = c ? atomicAdd(&gcur[b], c) : 0;
    }
    __syncthreads();
    #pragma unroll
    for (int u = 0; u < 16; ++u){
        int e = c0 + u * 256 + tid;
        if (e < E){
            int t = tgt[e];
            int b = t >> BSH;
            int p = gb[b] + atomicAdd(&lc[b], 1);
            uint4 o;
            o.x = (unsigned)src[e] | pack_bf16_hi(asp[e] * wsp[e]);
            o.y = (pack_bf16_hi(actx[e] * wctx[e]) >> 16) | pack_bf16_hi(alat[e] * wlat[e]);
            o.z = (unsigned)t;
            o.w = 0u;
            binned[p] = o;
        }
    }
}

// ---------- pass 2: per-bucket CSR finalize (writes rs + final effo)
//            + fused per-target deg sums -> dinv_all for ALL layers ----------
__global__ __launch_bounds__(256) void k_bucket(
        const uint4* __restrict__ binned, const int* __restrict__ bbase,
        const float* __restrict__ dp,        // [L*3]
        uint2* __restrict__ effo, int* __restrict__ rs,
        float* __restrict__ dinv_all,        // [L][N][4] (padded float4)
        int N, int L){
    __shared__ int th[128], sc2[128], cur[128];
    __shared__ float sm[384];
    int tid = threadIdx.x;
    int b = blockIdx.x;
    int t0 = b << BSH;
    int ebeg = bbase[b], eend = bbase[b + 1];
    if (tid < 128) th[tid] = 0;
    for (int j = tid; j < 384; j += 256) sm[j] = 0.f;
    __syncthreads();
    for (int i = ebeg + tid; i < eend; i += 256)
        atomicAdd(&th[(int)binned[i].z - t0], 1);
    __syncthreads();
    int v = (tid < 128) ? th[tid] : 0;
    if (tid < 128) sc2[tid] = v;
    __syncthreads();
    for (int off = 1; off < 128; off <<= 1){
        int x = (tid >= off && tid < 128) ? sc2[tid - off] : 0;
        __syncthreads();
        if (tid < 128) sc2[tid] += x;
        __syncthreads();
    }
    if (tid < 128){
        int exv = sc2[tid] - v;
        cur[tid] = exv;
        int t = t0 + tid;
        if (t < N) rs[t] = ebeg + exv;
    }
    __syncthreads();
    for (int i = ebeg + tid; i < eend; i += 256){
        uint4 r = binned[i];
        int loc = (int)r.z - t0;
        int p = atomicAdd(&cur[loc], 1);
        uint2 o = {r.x, r.y};
        effo[ebeg + p] = o;
        atomicAdd(&sm[loc * 3 + 0], bf16hi_to_f32(r.x & 0xFFFF0000u));
        atomicAdd(&sm[loc * 3 + 1], bf16hi_to_f32(r.y << 16));
        atomicAdd(&sm[loc * 3 + 2], bf16hi_to_f32(r.y & 0xFFFF0000u));
    }
    __syncthreads();
    if (tid < 128){
        int t = t0 + tid;
        if (t < N){
            float d0 = fmaxf(1.f + sm[tid * 3 + 0], 1e-6f);
            float d1 = fmaxf(1.f + sm[tid * 3 + 1], 1e-6f);
            float d2 = fmaxf(1.f + sm[tid * 3 + 2], 1e-6f);
            for (int l = 0; l < L; ++l){
                size_t base = ((size_t)l * N + t) * 4;
                dinv_all[base + 0] = powf(d0, dp[l * 3 + 0]);
                dinv_all[base + 1] = powf(d1, dp[l * 3 + 1]);
                dinv_all[base + 2] = powf(d2, dp[l * 3 + 2]);
                dinv_all[base + 3] = 0.f;
            }
        }
    }
}

// ---------------- x (fp32) -> A'[:,0:128] (bf16, row stride 512) ----------------
__global__ void k_x2bf(const float* __restrict__ x, __hip_bfloat16* __restrict__ Ap, int n){
    int i = blockIdx.x * 256 + threadIdx.x;
    if (i < n) Ap[(size_t)(i >> 7) * 512 + (i & 127)] = __float2bfloat16(x[i]);
}

// ---------------- BT for ALL layers: BT[l][j][k], B = [W_self; W3[0..2]] ----------
__global__ void k_wcat(const float* __restrict__ Wself,  // [L,128,128] (k,j)
                       const float* __restrict__ W3,     // [L,3,128,128]
                       __hip_bfloat16* __restrict__ BT,  // [L][128][512]
                       int L){
    int i = blockIdx.x * 256 + threadIdx.x;
    if (i >= L * 65536) return;
    int l = i >> 16, r = i & 65535;
    int j = r >> 9, k = r & 511;
    float v;
    if (k < 128) v = Wself[l * 16384 + k * 128 + j];
    else {
        int c = (k >> 7) - 1, kk = k & 127;
        v = W3[l * 49152 + (c * 128 + kk) * 128 + j];
    }
    BT[i] = __float2bfloat16(v);
}

// ---------------- aggregate: Y_c[t] = dt_c * sum_e eff_c[e]*dinv_c[src]*x[src] ----
// 16 lanes per source row (16B dwordx4/lane): one VMEM instruction gathers 4 edges'
// rows (1KB). norm (eff*dinv[src]) folded in (k_normv eliminated). Accumulate
// 8 cols x 3 ch per lane; xor-shuffle (16,32) reduces the 4 edge-groups at the end.
__global__ __launch_bounds__(256) void k_msg(
        __hip_bfloat16* __restrict__ Ap,   // [N,512]: cols 0..127 = x (read), 128..511 = Y (write)
        const uint2* __restrict__ effo,    // [E] packed {src|e0, e1|e2}, CSR order
        const int* __restrict__ rs,        // [N+1]
        const float4* __restrict__ dinv4,  // [N] padded {d0,d1,d2,0} (this layer)
        int N){
    int w = threadIdx.x >> 6, lane = threadIdx.x & 63;
    int g = lane >> 4, c = lane & 15;      // edge-group, column-chunk
    int t = blockIdx.x * 4 + w;
    if (t >= N) return;
    int beg = rs[t], end = rs[t + 1];
    if (beg == end){
        if (g < 3){
            bf16x8 z = {0, 0, 0, 0, 0, 0, 0, 0};
            *(bf16x8*)(Ap + (size_t)t * 512 + 128 + g * 128 + c * 8) = z;
        }
        return;
    }
    float a0[8], a1[8], a2[8];
    #pragma unroll
    for (int j = 0; j < 8; ++j){ a0[j] = 0.f; a1[j] = 0.f; a2[j] = 0.f; }

    for (int i = beg; i < end; i += 8){
        int e0 = i + g, e1 = i + 4 + g;
        bool p0 = e0 < end, p1 = e1 < end;
        uint2 m0 = effo[p0 ? e0 : beg];
        uint2 m1 = effo[p1 ? e1 : beg];
        int s0 = (int)(m0.x & 0xFFFFu);
        int s1 = (int)(m1.x & 0xFFFFu);
        float4 d0 = dinv4[s0];
        float4 d1 = dinv4[s1];
        bf16x8 x0 = *(const bf16x8*)(Ap + (size_t)s0 * 512 + c * 8);
        bf16x8 x1 = *(const bf16x8*)(Ap + (size_t)s1 * 512 + c * 8);
        float n00 = 0.f, n01 = 0.f, n02 = 0.f, n10 = 0.f, n11 = 0.f, n12 = 0.f;
        if (p0){
            n00 = bf16hi_to_f32(m0.x & 0xFFFF0000u) * d0.x;
            n01 = bf16hi_to_f32(m0.y << 16)         * d0.y;
            n02 = bf16hi_to_f32(m0.y & 0xFFFF0000u) * d0.z;
        }
        if (p1){
            n10 = bf16hi_to_f32(m1.x & 0xFFFF0000u) * d1.x;
            n11 = bf16hi_to_f32(m1.y << 16)         * d1.y;
            n12 = bf16hi_to_f32(m1.y & 0xFFFF0000u) * d1.z;
        }
        const unsigned* u0 = (const unsigned*)&x0;
        const unsigned* u1 = (const unsigned*)&x1;
        #pragma unroll
        for (int k2 = 0; k2 < 4; ++k2){
            float f0a = __uint_as_float(u0[k2] << 16);
            float f0b = __uint_as_float(u0[k2] & 0xFFFF0000u);
            a0[2*k2]   += n00 * f0a; a0[2*k2+1] += n00 * f0b;
            a1[2*k2]   += n01 * f0a; a1[2*k2+1] += n01 * f0b;
            a2[2*k2]   += n02 * f0a; a2[2*k2+1] += n02 * f0b;
            float f1a = __uint_as_float(u1[k2] << 16);
            float f1b = __uint_as_float(u1[k2] & 0xFFFF0000u);
            a0[2*k2]   += n10 * f1a; a0[2*k2+1] += n10 * f1b;
            a1[2*k2]   += n11 * f1a; a1[2*k2+1] += n11 * f1b;
            a2[2*k2]   += n12 * f1a; a2[2*k2+1] += n12 * f1b;
        }
    }

    // reduce across the 4 edge-groups (lanes differing in bits 4,5)
    #pragma unroll
    for (int j = 0; j < 8; ++j){
        a0[j] += __shfl_xor(a0[j], 16); a0[j] += __shfl_xor(a0[j], 32);
        a1[j] += __shfl_xor(a1[j], 16); a1[j] += __shfl_xor(a1[j], 32);
        a2[j] += __shfl_xor(a2[j], 16); a2[j] += __shfl_xor(a2[j], 32);
    }

    float4 dt = dinv4[t];
    // group g writes channel g (static indexing only — no runtime-indexed arrays)
    float r[8];
    if (g == 0){
        #pragma unroll
        for (int j = 0; j < 8; ++j) r[j] = dt.x * a0[j];
    } else if (g == 1){
        #pragma unroll
        for (int j = 0; j < 8; ++j) r[j] = dt.y * a1[j];
    } else if (g == 2){
        #pragma unroll
        for (int j = 0; j < 8; ++j) r[j] = dt.z * a2[j];
    }
    if (g < 3){
        bf16x8 o;
        #pragma unroll
        for (int j = 0; j < 8; ++j)
            o[j] = (short)__bfloat16_as_ushort(__float2bfloat16(r[j]));
        *(bf16x8*)(Ap + (size_t)t * 512 + 128 + g * 128 + c * 8) = o;
    }
}

// ---------------- GEMM: out = A'[M,512] @ B[512,128] + bias; optional fused LN+ReLU
__global__ __launch_bounds__(256) void k_gemm(
        const __hip_bfloat16* __restrict__ A,   // [M,512] bf16
        const __hip_bfloat16* __restrict__ BT,  // [128,512] bf16 ([j][k])
        const float* __restrict__ bias,         // [128] fp32
        float* __restrict__ outbuf,             // [M,128] (doLN==0)
        int M, int doLN,
        const float* __restrict__ g, const float* __restrict__ b,
        __hip_bfloat16* __restrict__ Ap){       // (doLN==1)
    __shared__ __hip_bfloat16 As[128 * 128];
    __shared__ __hip_bfloat16 Bs[128 * 128];
    const int tid = threadIdx.x;
    const int row0 = blockIdx.x * 128;
    const int w = tid >> 6, lane = tid & 63;
    const int wm = (w & 1) * 64, wn = (w >> 1) * 64;
    const int lm = lane & 15, lq = lane >> 4;

    f32x4 acc[4][4];
    #pragma unroll
    for (int mt = 0; mt < 4; ++mt)
        #pragma unroll
        for (int nt = 0; nt < 4; ++nt)
            acc[mt][nt] = {0.f, 0.f, 0.f, 0.f};

    for (int kt = 0; kt < 4; ++kt){
        #pragma unroll
        for (int it = 0; it < 8; ++it){
            int v = it * 256 + tid;
            int r = v >> 4, c = v & 15;
            int soff = r * 128 + ((c ^ (r & 15)) << 3);
            int4 av = {0, 0, 0, 0};
            if (row0 + r < M)
                av = *(const int4*)(A + (size_t)(row0 + r) * 512 + kt * 128 + (c << 3));
            *(int4*)(&As[soff]) = av;
            int4 bv = *(const int4*)(BT + (size_t)r * 512 + kt * 128 + (c << 3));
            *(int4*)(&Bs[soff]) = bv;
        }
        __syncthreads();

        #pragma unroll
        for (int kk = 0; kk < 4; ++kk){
            int kc = kk * 4 + lq;
            bf16x8 a[4], b2[4];
            #pragma unroll
            for (int mt = 0; mt < 4; ++mt){
                int r = wm + mt * 16 + lm;
                a[mt] = *(const bf16x8*)(&As[r * 128 + ((kc ^ (r & 15)) << 3)]);
            }
            #pragma unroll
            for (int nt = 0; nt < 4; ++nt){
                int r = wn + nt * 16 + lm;
                b2[nt] = *(const bf16x8*)(&Bs[r * 128 + ((kc ^ (r & 15)) << 3)]);
            }
            #pragma unroll
            for (int mt = 0; mt < 4; ++mt)
                #pragma unroll
                for (int nt = 0; nt < 4; ++nt)
                    acc[mt][nt] = __builtin_amdgcn_mfma_f32_16x16x32_bf16(
                        a[mt], b2[nt], acc[mt][nt], 0, 0, 0);
        }
        __syncthreads();
    }

    if (!doLN){
        #pragma unroll
        for (int mt = 0; mt < 4; ++mt){
            #pragma unroll
            for (int nt = 0; nt < 4; ++nt){
                int col = wn + nt * 16 + lm;
                #pragma unroll
                for (int r = 0; r < 4; ++r){
                    int row = row0 + wm + mt * 16 + lq * 4 + r;
                    if (row < M)
                        outbuf[(size_t)row * 128 + col] = acc[mt][nt][r] + bias[col];
                }
            }
        }
    } else {
        // fused LN+ReLU epilogue. Reuse As for partial sums, Bs for mu/scale.
        float* S1 = (float*)As;          // [128][32] sum partials
        float* S2 = S1 + 4096;           // [128][32] sumsq partials
        float* MS = (float*)Bs;          // mu[128], sc[128]
        const int half = wn >> 6;        // 0 or 1
        const int slot = half * 16 + lm;
        float bv[4];
        #pragma unroll
        for (int nt = 0; nt < 4; ++nt) bv[nt] = bias[wn + nt * 16 + lm];
        #pragma unroll
        for (int mt = 0; mt < 4; ++mt){
            #pragma unroll
            for (int r = 0; r < 4; ++r){
                int rl = wm + mt * 16 + lq * 4 + r;
                float ps = 0.f, pq = 0.f;
                #pragma unroll
                for (int nt = 0; nt < 4; ++nt){
                    float v = acc[mt][nt][r] + bv[nt];
                    ps += v; pq += v * v;
                }
                S1[rl * 32 + slot] = ps;
                S2[rl * 32 + slot] = pq;
            }
        }
        __syncthreads();
        if (tid < 128){
            float s = 0.f, sq = 0.f;
            #pragma unroll
            for (int j = 0; j < 32; ++j){
                s  += S1[tid * 32 + j];
                sq += S2[tid * 32 + j];
            }
            float mu = s * (1.0f / 128.0f);
            float var = sq * (1.0f / 128.0f) - mu * mu;
            MS[tid] = mu;
            MS[128 + tid] = rsqrtf(var + 1e-5f);
        }
        __syncthreads();
        float gv[4], bbv[4];
        #pragma unroll
        for (int nt = 0; nt < 4; ++nt){
            int col = wn + nt * 16 + lm;
            gv[nt] = g[col]; bbv[nt] = b[col];
        }
        #pragma unroll
        for (int mt = 0; mt < 4; ++mt){
            #pragma unroll
            for (int r = 0; r < 4; ++r){
                int rl = wm + mt * 16 + lq * 4 + r;
                int row = row0 + rl;
                if (row < M){
                    float mu = MS[rl], sc = MS[128 + rl];
                    #pragma unroll
                    for (int nt = 0; nt < 4; ++nt){
                        int col = wn + nt * 16 + lm;
                        float v = acc[mt][nt][r] + bv[nt];
                        float y = fmaxf((v - mu) * sc * gv[nt] + bbv[nt], 0.0f);
                        Ap[(size_t)row * 512 + col] = __float2bfloat16(y);
                    }
                }
            }
        }
    }
}

extern "C" void kernel_launch(void* const* d_in, const int* in_sizes, int n_in,
                              void* d_out, int out_size, void* d_ws, size_t ws_size,
                              hipStream_t stream) {
    const float* x     = (const float*)d_in[0];
    const int*   ei    = (const int*)d_in[1];
    const float* asp   = (const float*)d_in[2];
    const float* actx  = (const float*)d_in[3];
    const float* alat  = (const float*)d_in[4];
    const float* wsp   = (const float*)d_in[5];
    const float* wctx  = (const float*)d_in[6];
    const float* wlat  = (const float*)d_in[7];
    const float* W3    = (const float*)d_in[8];
    const float* Wself = (const float*)d_in[9];
    const float* bias  = (const float*)d_in[10];
    const float* dpow  = (const float*)d_in[11];
    const float* lng   = (const float*)d_in[12];
    const float* lnb   = (const float*)d_in[13];

    const int N = in_sizes[0] / 128;
    const int E = in_sizes[1] / 2;
    const int L = in_sizes[8] / (3 * 128 * 128);
    const int NB = cdiv(N, BK);
    const int* src = ei;
    const int* tgt = ei + E;

    // workspace carve (256B-aligned)
    char* p = (char*)d_ws;
    auto alloc = [&](size_t bytes) -> void* {
        void* r = (void*)p;
        p += (bytes + 255) & ~(size_t)255;
        return r;
    };
    int*   rs       = (int*)  alloc((size_t)(N + 1) * 4);
    int*   gcnt     = (int*)  alloc(1024 * 4);
    int*   bbase    = (int*)  alloc(1025 * 4);
    int*   gcur     = (int*)  alloc(1024 * 4);
    uint2* effo     = (uint2*)alloc((size_t)E * 8);
    float* dinv_all = (float*)alloc((size_t)L * N * 4 * 4);   // [L][N][4] padded
    __hip_bfloat16* Ap = (__hip_bfloat16*)alloc((size_t)N * 512 * 2);  // [x|Y0|Y1|Y2]
    __hip_bfloat16* BT = (__hip_bfloat16*)alloc((size_t)L * 128 * 512 * 2);
    // binned (E*16B) aliased onto Ap: dead before k_x2bf writes Ap (stream-ordered).
    // Keeps total footprint BELOW the previous session's (~61MB vs ~77MB).
    uint4* binned = (uint4*)Ap;

    // ---- prep: bucketed counting-sort CSR build (deg/dinv fused into k_bucket) ----
    hipMemsetAsync(gcnt, 0, 1024 * 4, stream);
    k_bcnt0 <<<cdiv(E, 4096), 256, 0, stream>>>(tgt, gcnt, E, NB);
    k_bscan <<<1, 256, 0, stream>>>(gcnt, bbase, gcur, rs, N, E);
    k_bin   <<<cdiv(E, 4096), 256, 0, stream>>>(src, tgt, asp, actx, alat, wsp, wctx, wlat,
                                                gcur, binned, E, NB);
    k_bucket<<<NB, 256, 0, stream>>>(binned, bbase, dpow, effo, rs, dinv_all, N, L);
    k_x2bf  <<<cdiv(N * 128, 256), 256, 0, stream>>>(x, Ap, N * 128);
    k_wcat  <<<cdiv(L * 65536, 256), 256, 0, stream>>>(Wself, W3, BT, L);

    // ---- layers ----
    for (int l = 0; l < L; ++l){
        int doLN = (l < L - 1) ? 1 : 0;
        const float4* dinv_l = (const float4*)dinv_all + (size_t)l * N;
        k_msg <<<cdiv(N, 4), 256, 0, stream>>>(Ap, effo, rs, dinv_l, N);
        k_gemm<<<cdiv(N, 128), 256, 0, stream>>>(Ap, BT + (size_t)l * 65536,
                                                 bias + l * 128, (float*)d_out, N,
                                                 doLN, lng, lnb, Ap);
    }
}